// Round 3
// baseline (442.797 us; speedup 1.0000x reference)
//
#include <hip/hip_runtime.h>

#define KCODES 512
#define DIM 64
#define NB 32
#define NH 64
#define NW 64
#define NPTS (NB*NH*NW)     // 131072
#define HW (NH*NW)          // 4096

// ---- output layout (floats) ----
#define O_OUT  0
#define O_LOSS 8388608
#define O_IDX  8388609
#define O_EMB  8519681
#define O_M    8552449
#define O_MM   8585217

// ---- workspace layout (floats) ----
#define W_DM   0                    // K*D segment sums
#define W_CNT  (KCODES*DIM)         // 32768: K counts
#define W_LOSS (W_CNT + KCODES)     // 33280: loss accumulator
#define W_C    (W_LOSS + 1)         // 33281: K codeword sq-norms
#define W_NEWM (W_C + KCODES)       // 33793: K smoothed new_M
#define W_TOTAL (W_NEWM + KCODES)   // 34305 floats ~ 137 KB

__global__ void cnorm_kernel(const float* __restrict__ emb, float* __restrict__ ws) {
    int k = blockIdx.x * blockDim.x + threadIdx.x;
    if (k >= KCODES) return;
    float s = 0.f;
    #pragma unroll
    for (int d = 0; d < DIM; ++d) { float v = emb[k*DIM + d]; s += v*v; }
    ws[W_C + k] = s;
}

// Dist phase reads emb/cns with WAVE-UNIFORM addresses -> compiler emits
// s_load through the scalar cache, v_fma consumes the SGPR operand directly.
// No LDS in the hot loop (round-2 was LDS-issue-bound: 8 waves x 16
// ds_read_b128 x 12cyc = 1536 cyc/CU per kk vs 280 cyc VALU).
__global__ __launch_bounds__(256, 2) void assign_kernel(
    const float* __restrict__ enc, const float* __restrict__ emb,
    const float* __restrict__ cns,   // = ws + W_C (disjoint from dm writes)
    float* __restrict__ out, float* __restrict__ ws)
{
    __shared__ float T[4][64][17];    // per-wave transpose tile, 17-stride pad
    const int t = threadIdx.x;
    const int w = t & 63;                       // lane = W coordinate (coalesced)
    const int wv = t >> 6;                      // wave id 0..3
    const int R = blockIdx.x * 4 + wv;          // (b,h) row index, 0..2047
    const int b = R >> 6, h = R & 63;

    // load this point's D=64 vector (each load instruction is a coalesced 256B)
    const float* px = enc + (size_t)b * DIM * HW + h * NW + w;
    float x[DIM];
    #pragma unroll
    for (int d = 0; d < DIM; ++d) x[d] = px[(size_t)d * HW];

    // ---- distance phase: scores bit-identical to rounds 1/2 ----
    float best = 3.402823466e38f;
    int bidx = 0;
    #pragma unroll 2
    for (int kk = 0; kk < KCODES; ++kk) {
        const float4* er = (const float4*)(emb + kk * DIM);   // uniform -> s_load
        float cn = cns[kk];                                   // uniform -> s_load
        float a0 = 0.f, a1 = 0.f, a2 = 0.f, a3 = 0.f;         // 4 indep FMA chains
        #pragma unroll
        for (int q = 0; q < 16; ++q) {
            float4 e = er[q];
            a0 += x[4*q+0]*e.x; a1 += x[4*q+1]*e.y;
            a2 += x[4*q+2]*e.z; a3 += x[4*q+3]*e.w;
        }
        float score = cn - 2.f*((a0+a1)+(a2+a3));
        if (score < best) { best = score; bidx = kk; }  // strict < = first-min
    }
    __syncthreads();   // all waves done before T-tile use

    // ---- epilogue: wave-transposed scatter/gather ----
    float* po = out + O_OUT + (size_t)b * DIM * HW + h * NW + w;
    float* dm = ws + W_DM;
    const int pg = w >> 4;      // which of 4 points this lane serves
    const int dl = w & 15;      // dim-in-chunk
    float lsum = 0.f;

    #pragma unroll              // c must be compile-time: x[] stays in VGPRs (rule #20)
    for (int c = 0; c < 4; ++c) {
        // A: deposit own x chunk (row w)
        #pragma unroll
        for (int i = 0; i < 16; ++i) T[wv][w][i] = x[c*16 + i];
        __syncthreads();
        // B: transposed workers — 4 points x 16 contiguous dims per instruction
        #pragma unroll
        for (int jj = 0; jj < 16; ++jj) {
            int p = jj*4 + pg;
            int kb = __shfl(bidx, p, 64);
            float xv = T[wv][p][dl];
            int addr = kb*64 + c*16 + dl;
            atomicAdd(&dm[addr], xv);
            T[wv][p][dl] = emb[addr];   // same lane/addr overwrite: safe
        }
        __syncthreads();
        // C: un-transpose — coalesced quantized store + loss (reads own row)
        #pragma unroll
        for (int i = 0; i < 16; ++i) {
            float q = T[wv][w][i];
            po[(size_t)(c*16 + i) * HW] = q;
            float df = q - x[c*16 + i];
            lsum = fmaf(df, df, lsum);
        }
    }

    atomicAdd(&ws[W_CNT + bidx], 1.0f);
    out[O_IDX + (size_t)R*64 + w] = (float)bidx;

    // wave-reduce the loss partial (wave = 64 lanes)
    #pragma unroll
    for (int off = 32; off >= 1; off >>= 1) lsum += __shfl_down(lsum, off, 64);
    if (w == 0) atomicAdd(&ws[W_LOSS], lsum);
}

__global__ void finalizeA(const float* __restrict__ emaM,
                          float* __restrict__ out, float* __restrict__ ws)
{
    __shared__ float red[512];
    int k = threadIdx.x;  // 512 threads, one per codeword
    float nM = 0.99f * emaM[k] + 0.01f * ws[W_CNT + k];
    red[k] = nM;
    __syncthreads();
    for (int s = 256; s >= 1; s >>= 1) {
        if (k < s) red[k] += red[k + s];
        __syncthreads();
    }
    float Ntot = red[0];
    float sm = (nM + 1e-5f) / (Ntot + 1e-5f * (float)KCODES) * Ntot;
    ws[W_NEWM + k] = sm;
    out[O_MM + k] = sm;
    if (k == 0) out[O_LOSS] = 0.25f * ws[W_LOSS] / (float)((size_t)NPTS * DIM);
}

__global__ void finalizeB(const float* __restrict__ emam,
                          float* __restrict__ out, const float* __restrict__ ws)
{
    int i = blockIdx.x * blockDim.x + threadIdx.x;  // 0..32767
    int k = i >> 6;
    float nm = 0.99f * emam[i] + 0.01f * ws[W_DM + i];
    out[O_M + i] = nm;
    out[O_EMB + i] = nm / ws[W_NEWM + k];
}

extern "C" void kernel_launch(void* const* d_in, const int* in_sizes, int n_in,
                              void* d_out, int out_size, void* d_ws, size_t ws_size,
                              hipStream_t stream)
{
    const float* enc  = (const float*)d_in[0];
    const float* emb  = (const float*)d_in[1];
    const float* emam = (const float*)d_in[2];
    const float* emaM = (const float*)d_in[3];
    float* out = (float*)d_out;
    float* ws  = (float*)d_ws;

    hipMemsetAsync(ws, 0, (size_t)W_TOTAL * sizeof(float), stream);
    cnorm_kernel<<<2, 256, 0, stream>>>(emb, ws);
    assign_kernel<<<NPTS/256, 256, 0, stream>>>(enc, emb, ws + W_C, out, ws);
    finalizeA<<<1, 512, 0, stream>>>(emaM, out, ws);
    finalizeB<<<(KCODES*DIM)/256, 256, 0, stream>>>(emam, out, ws);
}